// Round 2
// baseline (4280.093 us; speedup 1.0000x reference)
//
#include <hip/hip_runtime.h>

// Problem constants
#define NB 16
#define NH 96
#define NW 320
#define NCIN 32

// ---------------------------------------------------------------------------
// Mask scatter: mask[b,y,x] = 1 for each active coord (duplicates benign)
// ---------------------------------------------------------------------------
__global__ void scatter_mask(const int* __restrict__ coords, unsigned char* __restrict__ mask, int n) {
    int i = blockIdx.x * blockDim.x + threadIdx.x;
    if (i < n) {
        int b = coords[i * 3 + 0];
        int y = coords[i * 3 + 1];
        int x = coords[i * 3 + 2];
        mask[(b * NH + y) * NW + x] = 1;
    }
}

// ---------------------------------------------------------------------------
// Weight transpose OIHW -> [k][ic][oc] (one-time, tiny)
// ---------------------------------------------------------------------------
__global__ void transpose_w(const float* __restrict__ w, float* __restrict__ wt, int IC, int OC) {
    int i = blockIdx.x * blockDim.x + threadIdx.x;
    int total = OC * IC * 9;
    if (i >= total) return;
    // dest layout: wt[(k*IC + ic)*OC + oc]
    int oc = i % OC;
    int ic = (i / OC) % IC;
    int k  = i / (OC * IC);
    wt[i] = w[(oc * IC + ic) * 9 + k];
}

// ---------------------------------------------------------------------------
// Conv 3x3 stride-2 pad-1, NHWC. Grid = posBlocks * (OC/OCB) oc-blocks.
// Block: PPB position-groups (P wide) x (OCB/OCT) oc-groups = 256 threads.
// All weights for this oc-block staged in LDS ONCE as [k][ic][ocb].
// Weight reads are wave-uniform broadcasts (PPB multiple of 32 keeps oc-group
// uniform-or-2way per wave). Bias added, NO relu (pool handles it).
// ---------------------------------------------------------------------------
template<int IC, int OC, int OCB, int OCT, int P, int PPB,
         int IH, int IW, int OH, int OW, bool MASKED>
__global__ __launch_bounds__(PPB*(OCB/OCT)) void conv3x3s2(
    const float* __restrict__ in, const float* __restrict__ wt,
    const float* __restrict__ bias, const unsigned char* __restrict__ mask,
    float* __restrict__ out)
{
    constexpr int GROUPS = OCB / OCT;
    constexpr int NT = PPB * GROUPS;
    constexpr int OWG = OW / P;
    constexpr int OCBLKS = OC / OCB;
    extern __shared__ float ldsw[];   // 9*IC*OCB floats

    const int t     = threadIdx.x;
    const int ocblk = blockIdx.x % OCBLKS;
    const int pblk  = blockIdx.x / OCBLKS;
    const int ocb0  = ocblk * OCB;

    const int pp = t % PPB;
    const int g  = t / PPB;
    const int s  = pblk * PPB + pp;
    const int oxg = s % OWG;
    const int oy  = (s / OWG) % OH;
    const int b   = s / (OWG * OH);
    const int ox0 = oxg * P;
    const int ocBase = g * OCT;

    // stage all weights for this oc-block (coalesced from pre-transposed wt)
    for (int idx = t; idx < 9 * IC * OCB; idx += NT) {
        int oc   = idx % OCB;
        int rest = idx / OCB;         // k*IC + ic
        ldsw[idx] = wt[rest * OC + ocb0 + oc];
    }
    __syncthreads();

    float acc[P][OCT];
    #pragma unroll
    for (int p = 0; p < P; p++)
        #pragma unroll
        for (int i = 0; i < OCT; i++) acc[p][i] = 0.f;

    #pragma unroll
    for (int ky = 0; ky < 3; ky++) {
        const int iy = oy * 2 - 1 + ky;
        const bool yok = (iy >= 0) && (iy < IH);
        #pragma unroll
        for (int kx = 0; kx < 3; kx++) {
            const int k = ky * 3 + kx;
            bool okp[P];
            const float* ib[P];
            #pragma unroll
            for (int p = 0; p < P; p++) {
                int ix = (ox0 + p) * 2 - 1 + kx;
                bool ok = yok && (ix >= 0) && (ix < IW);
                if (MASKED && ok) ok = (mask[(b * IH + iy) * IW + ix] != 0);
                okp[p] = ok;
                ib[p] = in + ((long)((b * IH + iy) * IW + ix)) * IC;
            }
            #pragma unroll
            for (int ic4 = 0; ic4 < IC / 4; ic4++) {
                float4 v[P];
                #pragma unroll
                for (int p = 0; p < P; p++)
                    v[p] = okp[p] ? ((const float4*)ib[p])[ic4]
                                  : make_float4(0.f, 0.f, 0.f, 0.f);
                #pragma unroll
                for (int j = 0; j < 4; j++) {
                    const float4* wr = (const float4*)&ldsw[(k * IC + ic4 * 4 + j) * OCB + ocBase];
                    float4 wv[OCT / 4];
                    #pragma unroll
                    for (int o = 0; o < OCT / 4; o++) wv[o] = wr[o];
                    #pragma unroll
                    for (int p = 0; p < P; p++) {
                        float vj = (j == 0) ? v[p].x : (j == 1) ? v[p].y : (j == 2) ? v[p].z : v[p].w;
                        #pragma unroll
                        for (int o = 0; o < OCT / 4; o++) {
                            acc[p][o * 4 + 0] = fmaf(vj, wv[o].x, acc[p][o * 4 + 0]);
                            acc[p][o * 4 + 1] = fmaf(vj, wv[o].y, acc[p][o * 4 + 1]);
                            acc[p][o * 4 + 2] = fmaf(vj, wv[o].z, acc[p][o * 4 + 2]);
                            acc[p][o * 4 + 3] = fmaf(vj, wv[o].w, acc[p][o * 4 + 3]);
                        }
                    }
                }
            }
        }
    }

    #pragma unroll
    for (int p = 0; p < P; p++) {
        const long sOut = (long)(b * OH + oy) * OW + (ox0 + p);
        float4* op = (float4*)(out + sOut * OC + ocb0 + ocBase);
        #pragma unroll
        for (int o = 0; o < OCT / 4; o++) {
            float4 r;
            r.x = acc[p][o * 4 + 0] + bias[ocb0 + ocBase + o * 4 + 0];
            r.y = acc[p][o * 4 + 1] + bias[ocb0 + ocBase + o * 4 + 1];
            r.z = acc[p][o * 4 + 2] + bias[ocb0 + ocBase + o * 4 + 2];
            r.w = acc[p][o * 4 + 3] + bias[ocb0 + ocBase + o * 4 + 3];
            op[o] = r;
        }
    }
}

// ---------------------------------------------------------------------------
// 3x3 stride-1 pad-1 maxpool (-inf pad) + ReLU, NHWC, float4 over channels
// ---------------------------------------------------------------------------
template<int C, int HH, int WW>
__global__ __launch_bounds__(256) void maxpool3_relu(const float* __restrict__ in, float* __restrict__ out) {
    constexpr int C4 = C / 4;
    int i = blockIdx.x * blockDim.x + threadIdx.x;
    if (i >= NB * HH * WW * C4) return;
    int c = i % C4;
    int x = (i / C4) % WW;
    int y = (i / (C4 * WW)) % HH;
    int b = i / (C4 * WW * HH);
    float4 m = make_float4(-3.0e38f, -3.0e38f, -3.0e38f, -3.0e38f);
    #pragma unroll
    for (int dy = -1; dy <= 1; dy++) {
        int yy = y + dy;
        if (yy < 0 || yy >= HH) continue;
        #pragma unroll
        for (int dx = -1; dx <= 1; dx++) {
            int xx = x + dx;
            if (xx < 0 || xx >= WW) continue;
            float4 v = ((const float4*)in)[((b * HH + yy) * WW + xx) * C4 + c];
            m.x = fmaxf(m.x, v.x);
            m.y = fmaxf(m.y, v.y);
            m.z = fmaxf(m.z, v.z);
            m.w = fmaxf(m.w, v.w);
        }
    }
    m.x = fmaxf(m.x, 0.f);
    m.y = fmaxf(m.y, 0.f);
    m.z = fmaxf(m.z, 0.f);
    m.w = fmaxf(m.w, 0.f);
    ((float4*)out)[i] = m;
}

// ---------------------------------------------------------------------------
// Permute pooled3 NHWC (b,y,x,c) -> xT[k][b], k = c*480 + y*40 + x (NCHW flat)
// ---------------------------------------------------------------------------
__global__ __launch_bounds__(256) void transpose_fc(const float* __restrict__ in, float* __restrict__ xT) {
    int i = blockIdx.x * blockDim.x + threadIdx.x;   // over 61440*16, (k,b) order
    if (i >= 61440 * NB) return;
    int b = i % NB;
    int k = i / NB;
    int c = k / 480;
    int r = k % 480;
    int y = r / 40;
    int x = r % 40;
    xT[i] = in[((b * 12 + y) * 40 + x) * 128 + c];
}

// ---------------------------------------------------------------------------
// FC stage 1: 64 oc-tiles (4 oc each) x 4 k-chunks = 256 blocks.
// Each thread strides k within its chunk; acc[4 oc][16 b]; padded-LDS reduce.
// ---------------------------------------------------------------------------
__global__ __launch_bounds__(256) void fc_stage1(const float* __restrict__ xT,
                                                 const float* __restrict__ fw,
                                                 float* __restrict__ partial)
{
    extern __shared__ float red[];   // 64 * 257 floats
    const int tile  = blockIdx.x >> 2;
    const int chunk = blockIdx.x & 3;
    const int t = threadIdx.x;
    const int K = 61440, KC = 15360;

    float acc[4][16];
    #pragma unroll
    for (int o = 0; o < 4; o++)
        #pragma unroll
        for (int bb = 0; bb < 16; bb++) acc[o][bb] = 0.f;

    const int k0 = chunk * KC;
    for (int k = k0 + t; k < k0 + KC; k += 256) {
        const float4* xp = (const float4*)(xT + (long)k * 16);
        float4 x0 = xp[0], x1 = xp[1], x2 = xp[2], x3 = xp[3];
        #pragma unroll
        for (int o = 0; o < 4; o++) {
            float w = fw[(long)(tile * 4 + o) * K + k];
            acc[o][0]  = fmaf(w, x0.x, acc[o][0]);
            acc[o][1]  = fmaf(w, x0.y, acc[o][1]);
            acc[o][2]  = fmaf(w, x0.z, acc[o][2]);
            acc[o][3]  = fmaf(w, x0.w, acc[o][3]);
            acc[o][4]  = fmaf(w, x1.x, acc[o][4]);
            acc[o][5]  = fmaf(w, x1.y, acc[o][5]);
            acc[o][6]  = fmaf(w, x1.z, acc[o][6]);
            acc[o][7]  = fmaf(w, x1.w, acc[o][7]);
            acc[o][8]  = fmaf(w, x2.x, acc[o][8]);
            acc[o][9]  = fmaf(w, x2.y, acc[o][9]);
            acc[o][10] = fmaf(w, x2.z, acc[o][10]);
            acc[o][11] = fmaf(w, x2.w, acc[o][11]);
            acc[o][12] = fmaf(w, x3.x, acc[o][12]);
            acc[o][13] = fmaf(w, x3.y, acc[o][13]);
            acc[o][14] = fmaf(w, x3.z, acc[o][14]);
            acc[o][15] = fmaf(w, x3.w, acc[o][15]);
        }
    }
    #pragma unroll
    for (int o = 0; o < 4; o++)
        #pragma unroll
        for (int bb = 0; bb < 16; bb++)
            red[(o * 16 + bb) * 257 + t] = acc[o][bb];
    __syncthreads();
    if (t < 64) {
        float ssum = 0.f;
        for (int i = 0; i < 256; i++) ssum += red[t * 257 + i];
        int o = t / 16, bb = t % 16;
        partial[(chunk * 256 + tile * 4 + o) * 16 + bb] = ssum;
    }
}

__global__ __launch_bounds__(256) void fc_reduce(const float* __restrict__ partial,
                                                 const float* __restrict__ fcb,
                                                 float* __restrict__ out)
{
    int i = blockIdx.x * blockDim.x + threadIdx.x;   // 4096
    if (i >= 4096) return;
    int oc = i / 16, b = i % 16;
    float s = fcb[oc];
    #pragma unroll
    for (int c = 0; c < 4; c++) s += partial[(c * 256 + oc) * 16 + b];
    out[b * 256 + oc] = fmaxf(s, 0.f);
}

// ---------------------------------------------------------------------------
extern "C" void kernel_launch(void* const* d_in, const int* in_sizes, int n_in,
                              void* d_out, int out_size, void* d_ws, size_t ws_size,
                              hipStream_t stream) {
    const float* input  = (const float*)d_in[0];
    const int*   coords = (const int*)d_in[1];
    const float* w1 = (const float*)d_in[2];
    const float* b1 = (const float*)d_in[3];
    const float* w2 = (const float*)d_in[4];
    const float* b2 = (const float*)d_in[5];
    const float* w3 = (const float*)d_in[6];
    const float* b3 = (const float*)d_in[7];
    const float* fcw = (const float*)d_in[8];
    const float* fcb = (const float*)d_in[9];
    float* outp = (float*)d_out;

    const int n_active = in_sizes[1] / 3;

    // workspace layout (floats)
    float* wT1 = (float*)d_ws;             // 9216
    float* wT2 = wT1 + 9216;               // 18432
    float* wT3 = wT2 + 18432;              // 73728
    float* R0  = wT3 + 73728;              // 3,932,160
    float* R1  = R0 + 3932160;             // 3,932,160
    float* partial = R1 + 3932160;         // 16384
    unsigned char* mask = (unsigned char*)(partial + 16384);   // 491,520 B

    hipMemsetAsync(mask, 0, NB * NH * NW, stream);
    transpose_w<<<36, 256, 0, stream>>>(w1, wT1, 32, 32);
    transpose_w<<<72, 256, 0, stream>>>(w2, wT2, 32, 64);
    transpose_w<<<288, 256, 0, stream>>>(w3, wT3, 64, 128);
    scatter_mask<<<(n_active + 255) / 256, 256, 0, stream>>>(coords, mask, n_active);

    // conv1: (16,96,320,32) -> (16,48,160,32)
    // IC=32 OC=32 OCB=32 OCT=16 P=2 PPB=128 -> 256 thr, 480 blocks, LDS 36 KB
    conv3x3s2<32, 32, 32, 16, 2, 128, 96, 320, 48, 160, true>
        <<<480, 256, 36864, stream>>>(input, wT1, b1, mask, R0);
    maxpool3_relu<32, 48, 160><<<3840, 256, 0, stream>>>(R0, R1);

    // conv2: (16,48,160,32) -> (16,24,80,64)
    // IC=32 OC=64 OCB=64 OCT=16 P=1 PPB=64 -> 256 thr, 480 blocks, LDS 72 KB
    conv3x3s2<32, 64, 64, 16, 1, 64, 48, 160, 24, 80, false>
        <<<480, 256, 73728, stream>>>(R1, wT2, b2, nullptr, R0);
    maxpool3_relu<64, 24, 80><<<1920, 256, 0, stream>>>(R0, R1);

    // conv3: (16,24,80,64) -> (16,12,40,128)
    // IC=64 OC=128 OCB=32 OCT=8 P=1 PPB=64 -> 256 thr, 120*4=480 blocks, LDS 72 KB
    conv3x3s2<64, 128, 32, 8, 1, 64, 24, 80, 12, 40, false>
        <<<480, 256, 73728, stream>>>(R1, wT3, b3, nullptr, R0);
    maxpool3_relu<128, 12, 40><<<960, 256, 0, stream>>>(R0, R1);

    // flatten permute + FC
    transpose_fc<<<3840, 256, 0, stream>>>(R1, R0);
    fc_stage1<<<256, 256, 64 * 257 * 4, stream>>>(R0, fcw, partial);
    fc_reduce<<<16, 256, 0, stream>>>(partial, fcb, outp);
}

// Round 3
// 364.866 us; speedup vs baseline: 11.7306x; 11.7306x over previous
//
#include <hip/hip_runtime.h>

// Problem constants
#define NB 16
#define NH 96
#define NW 320
#define NCIN 32

// ---------------------------------------------------------------------------
// Mask scatter: mask[b,y,x] = 1 for each active coord (duplicates benign)
// ---------------------------------------------------------------------------
__global__ void scatter_mask(const int* __restrict__ coords, unsigned char* __restrict__ mask, int n) {
    int i = blockIdx.x * blockDim.x + threadIdx.x;
    if (i < n) {
        int b = coords[i * 3 + 0];
        int y = coords[i * 3 + 1];
        int x = coords[i * 3 + 2];
        mask[(b * NH + y) * NW + x] = 1;
    }
}

// ---------------------------------------------------------------------------
// Weight transpose OIHW -> [k][ic][oc] (one-time, tiny)
// ---------------------------------------------------------------------------
__global__ void transpose_w(const float* __restrict__ w, float* __restrict__ wt, int IC, int OC) {
    int i = blockIdx.x * blockDim.x + threadIdx.x;
    int total = OC * IC * 9;
    if (i >= total) return;
    // dest layout: wt[(k*IC + ic)*OC + oc]
    int oc = i % OC;
    int ic = (i / OC) % IC;
    int k  = i / (OC * IC);
    wt[i] = w[(oc * IC + ic) * 9 + k];
}

// ---------------------------------------------------------------------------
// Conv 3x3 stride-2 pad-1, NHWC. Grid = posBlocks * (OC/OCB) oc-blocks.
// Block: PPB position-groups (P wide) x (OCB/OCT) oc-groups = 256 threads.
// All weights for this oc-block staged in LDS ONCE as [k][ic][ocb].
// ky/kx loops kept rolled (#pragma unroll 1): full unroll spilled to scratch
// in round 2 (VGPR 56->256, 3.5 GB scratch traffic, 10x regression).
// ---------------------------------------------------------------------------
template<int IC, int OC, int OCB, int OCT, int P, int PPB,
         int IH, int IW, int OH, int OW, bool MASKED>
__global__ __launch_bounds__(PPB*(OCB/OCT)) void conv3x3s2(
    const float* __restrict__ in, const float* __restrict__ wt,
    const float* __restrict__ bias, const unsigned char* __restrict__ mask,
    float* __restrict__ out)
{
    constexpr int GROUPS = OCB / OCT;
    constexpr int NT = PPB * GROUPS;
    constexpr int OWG = OW / P;
    constexpr int OCBLKS = OC / OCB;
    extern __shared__ float ldsw[];   // 9*IC*OCB floats

    const int t     = threadIdx.x;
    const int ocblk = blockIdx.x % OCBLKS;
    const int pblk  = blockIdx.x / OCBLKS;
    const int ocb0  = ocblk * OCB;

    const int pp = t % PPB;
    const int g  = t / PPB;
    const int s  = pblk * PPB + pp;
    const int oxg = s % OWG;
    const int oy  = (s / OWG) % OH;
    const int b   = s / (OWG * OH);
    const int ox0 = oxg * P;
    const int ocBase = g * OCT;

    // stage all weights for this oc-block (coalesced from pre-transposed wt)
    for (int idx = t; idx < 9 * IC * OCB; idx += NT) {
        int oc   = idx % OCB;
        int rest = idx / OCB;         // k*IC + ic
        ldsw[idx] = wt[rest * OC + ocb0 + oc];
    }
    __syncthreads();

    float acc[P][OCT];
    #pragma unroll
    for (int p = 0; p < P; p++)
        #pragma unroll
        for (int i = 0; i < OCT; i++) acc[p][i] = 0.f;

    #pragma unroll 1
    for (int ky = 0; ky < 3; ky++) {
        const int iy = oy * 2 - 1 + ky;
        const bool yok = (iy >= 0) && (iy < IH);
        #pragma unroll 1
        for (int kx = 0; kx < 3; kx++) {
            const int k = ky * 3 + kx;
            bool okp[P];
            const float* ib[P];
            #pragma unroll
            for (int p = 0; p < P; p++) {
                int ix = (ox0 + p) * 2 - 1 + kx;
                bool ok = yok && (ix >= 0) && (ix < IW);
                if (MASKED && ok) ok = (mask[(b * IH + iy) * IW + ix] != 0);
                okp[p] = ok;
                ib[p] = in + ((long)((b * IH + iy) * IW + ix)) * IC;
            }
            #pragma unroll 2
            for (int ic4 = 0; ic4 < IC / 4; ic4++) {
                float4 v[P];
                #pragma unroll
                for (int p = 0; p < P; p++)
                    v[p] = okp[p] ? ((const float4*)ib[p])[ic4]
                                  : make_float4(0.f, 0.f, 0.f, 0.f);
                #pragma unroll
                for (int j = 0; j < 4; j++) {
                    const float4* wr = (const float4*)&ldsw[(k * IC + ic4 * 4 + j) * OCB + ocBase];
                    float4 wv[OCT / 4];
                    #pragma unroll
                    for (int o = 0; o < OCT / 4; o++) wv[o] = wr[o];
                    #pragma unroll
                    for (int p = 0; p < P; p++) {
                        float vj = (j == 0) ? v[p].x : (j == 1) ? v[p].y : (j == 2) ? v[p].z : v[p].w;
                        #pragma unroll
                        for (int o = 0; o < OCT / 4; o++) {
                            acc[p][o * 4 + 0] = fmaf(vj, wv[o].x, acc[p][o * 4 + 0]);
                            acc[p][o * 4 + 1] = fmaf(vj, wv[o].y, acc[p][o * 4 + 1]);
                            acc[p][o * 4 + 2] = fmaf(vj, wv[o].z, acc[p][o * 4 + 2]);
                            acc[p][o * 4 + 3] = fmaf(vj, wv[o].w, acc[p][o * 4 + 3]);
                        }
                    }
                }
            }
        }
    }

    #pragma unroll
    for (int p = 0; p < P; p++) {
        const long sOut = (long)(b * OH + oy) * OW + (ox0 + p);
        float4* op = (float4*)(out + sOut * OC + ocb0 + ocBase);
        #pragma unroll
        for (int o = 0; o < OCT / 4; o++) {
            float4 r;
            r.x = acc[p][o * 4 + 0] + bias[ocb0 + ocBase + o * 4 + 0];
            r.y = acc[p][o * 4 + 1] + bias[ocb0 + ocBase + o * 4 + 1];
            r.z = acc[p][o * 4 + 2] + bias[ocb0 + ocBase + o * 4 + 2];
            r.w = acc[p][o * 4 + 3] + bias[ocb0 + ocBase + o * 4 + 3];
            op[o] = r;
        }
    }
}

// ---------------------------------------------------------------------------
// 3x3 stride-1 pad-1 maxpool (-inf pad) + ReLU, NHWC, float4 over channels
// ---------------------------------------------------------------------------
template<int C, int HH, int WW>
__global__ __launch_bounds__(256) void maxpool3_relu(const float* __restrict__ in, float* __restrict__ out) {
    constexpr int C4 = C / 4;
    int i = blockIdx.x * blockDim.x + threadIdx.x;
    if (i >= NB * HH * WW * C4) return;
    int c = i % C4;
    int x = (i / C4) % WW;
    int y = (i / (C4 * WW)) % HH;
    int b = i / (C4 * WW * HH);
    float4 m = make_float4(-3.0e38f, -3.0e38f, -3.0e38f, -3.0e38f);
    #pragma unroll
    for (int dy = -1; dy <= 1; dy++) {
        int yy = y + dy;
        if (yy < 0 || yy >= HH) continue;
        #pragma unroll
        for (int dx = -1; dx <= 1; dx++) {
            int xx = x + dx;
            if (xx < 0 || xx >= WW) continue;
            float4 v = ((const float4*)in)[((b * HH + yy) * WW + xx) * C4 + c];
            m.x = fmaxf(m.x, v.x);
            m.y = fmaxf(m.y, v.y);
            m.z = fmaxf(m.z, v.z);
            m.w = fmaxf(m.w, v.w);
        }
    }
    m.x = fmaxf(m.x, 0.f);
    m.y = fmaxf(m.y, 0.f);
    m.z = fmaxf(m.z, 0.f);
    m.w = fmaxf(m.w, 0.f);
    ((float4*)out)[i] = m;
}

// ---------------------------------------------------------------------------
// Permute pooled3 NHWC (b,y,x,c) -> xT[k][b], k = c*480 + y*40 + x (NCHW flat)
// ---------------------------------------------------------------------------
__global__ __launch_bounds__(256) void transpose_fc(const float* __restrict__ in, float* __restrict__ xT) {
    int i = blockIdx.x * blockDim.x + threadIdx.x;   // over 61440*16, (k,b) order
    if (i >= 61440 * NB) return;
    int b = i % NB;
    int k = i / NB;
    int c = k / 480;
    int r = k % 480;
    int y = r / 40;
    int x = r % 40;
    xT[i] = in[((b * 12 + y) * 40 + x) * 128 + c];
}

// ---------------------------------------------------------------------------
// FC stage 1: 64 oc-tiles (4 oc each) x 4 k-chunks = 256 blocks.
// Each thread strides k within its chunk; acc[4 oc][16 b]; padded-LDS reduce.
// ---------------------------------------------------------------------------
__global__ __launch_bounds__(256) void fc_stage1(const float* __restrict__ xT,
                                                 const float* __restrict__ fw,
                                                 float* __restrict__ partial)
{
    extern __shared__ float red[];   // 64 * 257 floats
    const int tile  = blockIdx.x >> 2;
    const int chunk = blockIdx.x & 3;
    const int t = threadIdx.x;
    const int K = 61440, KC = 15360;

    float acc[4][16];
    #pragma unroll
    for (int o = 0; o < 4; o++)
        #pragma unroll
        for (int bb = 0; bb < 16; bb++) acc[o][bb] = 0.f;

    const int k0 = chunk * KC;
    for (int k = k0 + t; k < k0 + KC; k += 256) {
        const float4* xp = (const float4*)(xT + (long)k * 16);
        float4 x0 = xp[0], x1 = xp[1], x2 = xp[2], x3 = xp[3];
        #pragma unroll
        for (int o = 0; o < 4; o++) {
            float w = fw[(long)(tile * 4 + o) * K + k];
            acc[o][0]  = fmaf(w, x0.x, acc[o][0]);
            acc[o][1]  = fmaf(w, x0.y, acc[o][1]);
            acc[o][2]  = fmaf(w, x0.z, acc[o][2]);
            acc[o][3]  = fmaf(w, x0.w, acc[o][3]);
            acc[o][4]  = fmaf(w, x1.x, acc[o][4]);
            acc[o][5]  = fmaf(w, x1.y, acc[o][5]);
            acc[o][6]  = fmaf(w, x1.z, acc[o][6]);
            acc[o][7]  = fmaf(w, x1.w, acc[o][7]);
            acc[o][8]  = fmaf(w, x2.x, acc[o][8]);
            acc[o][9]  = fmaf(w, x2.y, acc[o][9]);
            acc[o][10] = fmaf(w, x2.z, acc[o][10]);
            acc[o][11] = fmaf(w, x2.w, acc[o][11]);
            acc[o][12] = fmaf(w, x3.x, acc[o][12]);
            acc[o][13] = fmaf(w, x3.y, acc[o][13]);
            acc[o][14] = fmaf(w, x3.z, acc[o][14]);
            acc[o][15] = fmaf(w, x3.w, acc[o][15]);
        }
    }
    #pragma unroll
    for (int o = 0; o < 4; o++)
        #pragma unroll
        for (int bb = 0; bb < 16; bb++)
            red[(o * 16 + bb) * 257 + t] = acc[o][bb];
    __syncthreads();
    if (t < 64) {
        float ssum = 0.f;
        for (int i = 0; i < 256; i++) ssum += red[t * 257 + i];
        int o = t / 16, bb = t % 16;
        partial[(chunk * 256 + tile * 4 + o) * 16 + bb] = ssum;
    }
}

__global__ __launch_bounds__(256) void fc_reduce(const float* __restrict__ partial,
                                                 const float* __restrict__ fcb,
                                                 float* __restrict__ out)
{
    int i = blockIdx.x * blockDim.x + threadIdx.x;   // 4096
    if (i >= 4096) return;
    int oc = i / 16, b = i % 16;
    float s = fcb[oc];
    #pragma unroll
    for (int c = 0; c < 4; c++) s += partial[(c * 256 + oc) * 16 + b];
    out[b * 256 + oc] = fmaxf(s, 0.f);
}

// ---------------------------------------------------------------------------
extern "C" void kernel_launch(void* const* d_in, const int* in_sizes, int n_in,
                              void* d_out, int out_size, void* d_ws, size_t ws_size,
                              hipStream_t stream) {
    const float* input  = (const float*)d_in[0];
    const int*   coords = (const int*)d_in[1];
    const float* w1 = (const float*)d_in[2];
    const float* b1 = (const float*)d_in[3];
    const float* w2 = (const float*)d_in[4];
    const float* b2 = (const float*)d_in[5];
    const float* w3 = (const float*)d_in[6];
    const float* b3 = (const float*)d_in[7];
    const float* fcw = (const float*)d_in[8];
    const float* fcb = (const float*)d_in[9];
    float* outp = (float*)d_out;

    const int n_active = in_sizes[1] / 3;

    // workspace layout (floats)
    float* wT1 = (float*)d_ws;             // 9216
    float* wT2 = wT1 + 9216;               // 18432
    float* wT3 = wT2 + 18432;              // 73728
    float* R0  = wT3 + 73728;              // 3,932,160
    float* R1  = R0 + 3932160;             // 3,932,160
    float* partial = R1 + 3932160;         // 16384
    unsigned char* mask = (unsigned char*)(partial + 16384);   // 491,520 B

    hipMemsetAsync(mask, 0, NB * NH * NW, stream);
    transpose_w<<<36, 256, 0, stream>>>(w1, wT1, 32, 32);
    transpose_w<<<72, 256, 0, stream>>>(w2, wT2, 32, 64);
    transpose_w<<<288, 256, 0, stream>>>(w3, wT3, 64, 128);
    scatter_mask<<<(n_active + 255) / 256, 256, 0, stream>>>(coords, mask, n_active);

    // conv1: (16,96,320,32) -> (16,48,160,32)
    // IC=32 OC=32 OCB=32 OCT=16 P=2 PPB=128 -> 256 thr, 480 blocks, LDS 36 KB
    conv3x3s2<32, 32, 32, 16, 2, 128, 96, 320, 48, 160, true>
        <<<480, 256, 36864, stream>>>(input, wT1, b1, mask, R0);
    maxpool3_relu<32, 48, 160><<<3840, 256, 0, stream>>>(R0, R1);

    // conv2: (16,48,160,32) -> (16,24,80,64)
    // IC=32 OC=64 OCB=64 OCT=16 P=1 PPB=64 -> 256 thr, 480 blocks, LDS 72 KB
    conv3x3s2<32, 64, 64, 16, 1, 64, 48, 160, 24, 80, false>
        <<<480, 256, 73728, stream>>>(R1, wT2, b2, nullptr, R0);
    maxpool3_relu<64, 24, 80><<<1920, 256, 0, stream>>>(R0, R1);

    // conv3: (16,24,80,64) -> (16,12,40,128)
    // IC=64 OC=128 OCB=32 OCT=8 P=1 PPB=64 -> 256 thr, 120*4=480 blocks, LDS 72 KB
    conv3x3s2<64, 128, 32, 8, 1, 64, 24, 80, 12, 40, false>
        <<<480, 256, 73728, stream>>>(R1, wT3, b3, nullptr, R0);
    maxpool3_relu<128, 12, 40><<<960, 256, 0, stream>>>(R0, R1);

    // flatten permute + FC
    transpose_fc<<<3840, 256, 0, stream>>>(R1, R0);
    fc_stage1<<<256, 256, 64 * 257 * 4, stream>>>(R0, fcw, partial);
    fc_reduce<<<16, 256, 0, stream>>>(partial, fcb, outp);
}